// Round 11
// baseline (340.501 us; speedup 1.0000x reference)
//
#include <hip/hip_runtime.h>
#include <cstddef>
#include <cstdint>

#define L_SEQ 4096
#define EMB   1024
#define NH    16
#define HD    64
#define N3    3072
#define CHUNK 64
#define NCHUNK 64
#define EPS 1e-6f

typedef __attribute__((ext_vector_type(8))) short   bf16x8;
typedef __attribute__((ext_vector_type(4))) short   bf16x4;
typedef __attribute__((ext_vector_type(4))) float   floatx4;

#define AS1 __attribute__((address_space(1)))
#define AS3 __attribute__((address_space(3)))

__device__ __forceinline__ void gload_lds16(const void* g, void* l) {
    __builtin_amdgcn_global_load_lds((AS1 const unsigned int*)g,
                                     (AS3 unsigned int*)l, 16, 0, 0);
}

// round-to-nearest-even fp32 -> bf16 bits
__device__ __forceinline__ short f2bf(float f) {
    union { float f; unsigned u; } a; a.f = f;
    unsigned r = a.u + 0x7fffu + ((a.u >> 16) & 1u);
    return (short)(r >> 16);
}
__device__ __forceinline__ float bf2f(short s) {
    union { unsigned u; float f; } a; a.u = ((unsigned)(unsigned short)s) << 16;
    return a.f;
}

// ---------------------------------------------------------------------------
// K0: fused prep — blocks [0,2048): x->bf16; [2048,2816): qkv_w^T;
// [2816,3072): out_w^T. Block 0 also zeroes the per-head scan counters
// (d_ws is re-poisoned to 0xAA before every launch).
// ---------------------------------------------------------------------------
__device__ __forceinline__ void transpose_tile(const float* __restrict__ W,
                                               short* __restrict__ WT,
                                               int K, int N, int bx, int by,
                                               float (*t)[65], int tid)
{
    const int r  = tid >> 4;
    const int c4 = (tid & 15) << 2;
#pragma unroll
    for (int s = 0; s < 4; ++s) {
        const int k = r + s * 16;
        const floatx4 v = *(const floatx4*)&W[(size_t)(by * 64 + k) * N + bx * 64 + c4];
        t[k][c4 + 0] = v[0]; t[k][c4 + 1] = v[1];
        t[k][c4 + 2] = v[2]; t[k][c4 + 3] = v[3];
    }
    __syncthreads();
#pragma unroll
    for (int s = 0; s < 4; ++s) {
        const int n = r + s * 16;
        bf16x4 o;
        o[0] = f2bf(t[c4 + 0][n]); o[1] = f2bf(t[c4 + 1][n]);
        o[2] = f2bf(t[c4 + 2][n]); o[3] = f2bf(t[c4 + 3][n]);
        *(bf16x4*)&WT[(size_t)(bx * 64 + n) * K + by * 64 + c4] = o;
    }
}

__global__ __launch_bounds__(256)
void prep(const float* __restrict__ x, short* __restrict__ xb,
          const float* __restrict__ qkv_w, short* __restrict__ qwt,
          const float* __restrict__ out_w, short* __restrict__ owt,
          int* __restrict__ cnt)
{
    __shared__ float t[64][65];
    const int b = blockIdx.x;
    const int tid = threadIdx.x;
    if (b == 0 && tid < NH) cnt[tid] = 0;
    if (b < 2048) {
        const int i = b * 256 + tid;
        const floatx4 a = *(const floatx4*)(x + (size_t)i * 8);
        const floatx4 c = *(const floatx4*)(x + (size_t)i * 8 + 4);
        bf16x8 o;
        o[0] = f2bf(a[0]); o[1] = f2bf(a[1]); o[2] = f2bf(a[2]); o[3] = f2bf(a[3]);
        o[4] = f2bf(c[0]); o[5] = f2bf(c[1]); o[6] = f2bf(c[2]); o[7] = f2bf(c[3]);
        *(bf16x8*)(xb + (size_t)i * 8) = o;
    } else if (b < 2048 + 768) {
        const int u = b - 2048;
        transpose_tile(qkv_w, qwt, EMB, N3, u % 48, u / 48, t, tid);
    } else {
        const int u = b - 2816;
        transpose_tile(out_w, owt, EMB, EMB, u & 15, u >> 4, t, tid);
    }
}

// ---------------------------------------------------------------------------
// K1: qkv GEMM, 128x128 tile, double-panel K-step (16 barrier pairs).
// Epilogue: bias + elu+1 on q/k, LDS repack, coalesced bf16x8 scatter.
// ---------------------------------------------------------------------------
#define CST 136

__global__ __launch_bounds__(256)
void mfma_gemm_qkv(const short* __restrict__ A, const short* __restrict__ BT,
                   const float* __restrict__ bias,
                   short* __restrict__ OQ, short* __restrict__ OK,
                   short* __restrict__ OV, int N, int K)
{
    __shared__ __align__(16) short smem[128 * CST];
    short* pan[4] = { smem, smem + 4096, smem + 8192, smem + 12288 };
    const int tid  = threadIdx.x;
    const int lane = tid & 63;
    const int wave = tid >> 6;
    const int wm = (wave >> 1) * 64;
    const int wn = (wave & 1) * 64;
    const int bx = blockIdx.x;
    const int by = blockIdx.y;
    const int frow = lane & 15;
    const int quad = lane >> 4;
    const int fko  = quad << 3;

    const short* Ab = A  + (size_t)(by * 128) * K;
    const short* Bb = BT + (size_t)(bx * 128) * K;

    floatx4 acc[4][4] = {};

    for (int k0 = 0; k0 < K; k0 += 64) {
#pragma unroll
        for (int p = 0; p < 2; ++p) {
            const int kp = k0 + p * 32;
#pragma unroll
            for (int q = 0; q < 2; ++q) {
                const int ia = q * 256 + tid;
                const int row = ia >> 2;
                const int kc  = (ia & 3) << 3;
                gload_lds16(Ab + (size_t)row * K + kp + kc, &pan[p * 2 + 0][ia << 3]);
                gload_lds16(Bb + (size_t)row * K + kp + kc, &pan[p * 2 + 1][ia << 3]);
            }
        }
        __syncthreads();
#pragma unroll
        for (int p = 0; p < 2; ++p) {
            bf16x8 af[4], bfv[4];
#pragma unroll
            for (int mi = 0; mi < 4; ++mi)
                af[mi] = *(const bf16x8*)&pan[p * 2 + 0][(wm + mi * 16 + frow) * 32 + fko];
#pragma unroll
            for (int ni = 0; ni < 4; ++ni)
                bfv[ni] = *(const bf16x8*)&pan[p * 2 + 1][(wn + ni * 16 + frow) * 32 + fko];
#pragma unroll
            for (int mi = 0; mi < 4; ++mi)
#pragma unroll
                for (int ni = 0; ni < 4; ++ni)
                    acc[mi][ni] = __builtin_amdgcn_mfma_f32_16x16x32_bf16(
                        af[mi], bfv[ni], acc[mi][ni], 0, 0, 0);
        }
        __syncthreads();
    }

    const int rq = quad << 2;
#pragma unroll
    for (int ni = 0; ni < 4; ++ni) {
        const int n = bx * 128 + wn + ni * 16 + frow;
        const float bv = bias[n];
        const bool do_elu = (n >> 10) < 2;
#pragma unroll
        for (int mi = 0; mi < 4; ++mi)
#pragma unroll
            for (int r = 0; r < 4; ++r) {
                float v = acc[mi][ni][r] + bv;
                if (do_elu) v = (v > 0.f) ? (v + 1.f) : __expf(v);
                smem[(wm + mi * 16 + rq + r) * CST + wn + ni * 16 + frow] = f2bf(v);
            }
    }
    __syncthreads();
#pragma unroll
    for (int t = 0; t < 8; ++t) {
        const int idx = t * 256 + tid;
        const int mm = idx >> 4;
        const int c8 = (idx & 15) << 3;
        const bf16x8 val = *(const bf16x8*)&smem[mm * CST + c8];
        const int n0 = bx * 128 + c8;
        const int rsel = n0 >> 10;
        const int h  = (n0 & 1023) >> 6;
        const int d  = n0 & 63;
        short* base = (rsel == 0) ? OQ : (rsel == 1 ? OK : OV);
        *(bf16x8*)&base[((size_t)(h * L_SEQ + by * 128 + mm)) * HD + d] = val;
    }
}

// ---------------------------------------------------------------------------
// K5: out-projection GEMM, 64x128 tile (512 blocks = 2/CU), double-panel.
// ---------------------------------------------------------------------------
__global__ __launch_bounds__(256)
void mfma_gemm_out(const short* __restrict__ A, const short* __restrict__ BT,
                   const float* __restrict__ bias, float* __restrict__ OF,
                   int N, int K)
{
    __shared__ __align__(16) short smem[12288];
    short* pan[4] = { smem, smem + 2048, smem + 6144, smem + 8192 };
    const int tid  = threadIdx.x;
    const int lane = tid & 63;
    const int wave = tid >> 6;
    const int wm = (wave >> 1) * 32;
    const int wn = (wave & 1) * 64;
    const int bx = blockIdx.x;
    const int by = blockIdx.y;
    const int frow = lane & 15;
    const int quad = lane >> 4;
    const int fko  = quad << 3;

    const short* Ab = A  + (size_t)(by * 64) * K;
    const short* Bb = BT + (size_t)(bx * 128) * K;

    floatx4 acc[2][4] = {};

    for (int k0 = 0; k0 < K; k0 += 64) {
#pragma unroll
        for (int p = 0; p < 2; ++p) {
            const int kp = k0 + p * 32;
            {
                const int row = tid >> 2;
                const int kc  = (tid & 3) << 3;
                gload_lds16(Ab + (size_t)row * K + kp + kc, &pan[p * 2 + 0][tid << 3]);
            }
#pragma unroll
            for (int q = 0; q < 2; ++q) {
                const int ib = q * 256 + tid;
                const int row = ib >> 2;
                const int kc  = (ib & 3) << 3;
                gload_lds16(Bb + (size_t)row * K + kp + kc, &pan[p * 2 + 1][ib << 3]);
            }
        }
        __syncthreads();
#pragma unroll
        for (int p = 0; p < 2; ++p) {
            bf16x8 af[2], bfv[4];
#pragma unroll
            for (int mi = 0; mi < 2; ++mi)
                af[mi] = *(const bf16x8*)&pan[p * 2 + 0][(wm + mi * 16 + frow) * 32 + fko];
#pragma unroll
            for (int ni = 0; ni < 4; ++ni)
                bfv[ni] = *(const bf16x8*)&pan[p * 2 + 1][(wn + ni * 16 + frow) * 32 + fko];
#pragma unroll
            for (int mi = 0; mi < 2; ++mi)
#pragma unroll
                for (int ni = 0; ni < 4; ++ni)
                    acc[mi][ni] = __builtin_amdgcn_mfma_f32_16x16x32_bf16(
                        af[mi], bfv[ni], acc[mi][ni], 0, 0, 0);
        }
        __syncthreads();
    }

    const int rq = quad << 2;
#pragma unroll
    for (int ni = 0; ni < 4; ++ni) {
        const int n = bx * 128 + wn + ni * 16 + frow;
        const float bv = bias[n];
#pragma unroll
        for (int mi = 0; mi < 2; ++mi)
#pragma unroll
            for (int r = 0; r < 4; ++r) {
                const int m = by * 64 + wm + mi * 16 + rq + r;
                OF[(size_t)m * N + n] = acc[mi][ni][r] + bv;
            }
    }
}

// ---------------------------------------------------------------------------
// K2: per-(head,chunk) state sums (MFMA) + FUSED exclusive prefix scan.
// Each block writes S_c^T / z_c, fences, bumps cnt[h]; the LAST finisher of
// each head (unique, non-blocking -> no co-residency assumption, no hang)
// performs the 64-chunk exclusive scan into S0b (rows 0..63 = S0^T, row 64
// = z0). Eliminates the separate prefix_scan kernel + one launch gap.
// ---------------------------------------------------------------------------
#define SP 72

__global__ __launch_bounds__(256)
void chunk_state(const short* __restrict__ Kb, const short* __restrict__ Vb,
                 short* __restrict__ ScTb, float* __restrict__ zc,
                 short* __restrict__ S0b, int* __restrict__ cnt)
{
    __shared__ __align__(16) short Vt[64 * SP];   // V^T: rows e, cols l
    __shared__ __align__(16) short Kt[64 * SP];   // K'^T: rows d, cols l
    __shared__ int isLast;
    const int c = blockIdx.x, h = blockIdx.y;
    const int tid = threadIdx.x, lane = tid & 63, wave = tid >> 6;
    const int frow = lane & 15;
    const int quad = lane >> 4;
    const int fko  = quad << 3;
    const int wm   = wave << 4;
    const short* Kg = Kb + ((size_t)h * L_SEQ + (size_t)c * CHUNK) * HD;
    const short* Vg = Vb + ((size_t)h * L_SEQ + (size_t)c * CHUNK) * HD;

#pragma unroll
    for (int q = 0; q < 2; ++q) {
        const int idx = q * 256 + tid;            // 512 chunks of 8
        const int l = idx >> 3, c8 = (idx & 7) << 3;
        const bf16x8 vv = *(const bf16x8*)&Vg[l * 64 + c8];
        const bf16x8 kk = *(const bf16x8*)&Kg[l * 64 + c8];
#pragma unroll
        for (int j = 0; j < 8; ++j) {
            Vt[(c8 + j) * SP + l] = vv[j];
            Kt[(c8 + j) * SP + l] = kk[j];
        }
    }
    __syncthreads();

    const bf16x8 af0 = *(const bf16x8*)&Vt[(wm + frow) * SP + fko];
    const bf16x8 af1 = *(const bf16x8*)&Vt[(wm + frow) * SP + 32 + fko];

    floatx4 acc[4] = {};
#pragma unroll
    for (int n = 0; n < 4; ++n) {
        const bf16x8 kf0 = *(const bf16x8*)&Kt[(n * 16 + frow) * SP + fko];
        const bf16x8 kf1 = *(const bf16x8*)&Kt[(n * 16 + frow) * SP + 32 + fko];
        acc[n] = __builtin_amdgcn_mfma_f32_16x16x32_bf16(af0, kf0, acc[n], 0, 0, 0);
        acc[n] = __builtin_amdgcn_mfma_f32_16x16x32_bf16(af1, kf1, acc[n], 0, 0, 0);
    }

    short* Sout = ScTb + (size_t)(h * NCHUNK + c) * 4096;
#pragma unroll
    for (int n = 0; n < 4; ++n)
#pragma unroll
        for (int r = 0; r < 4; ++r) {
            const int e = wm + quad * 4 + r;
            const int d = n * 16 + frow;
            Sout[e * 64 + d] = f2bf(acc[n][r]);
        }

    if (wave == 0) {   // z[d] = sum_l K'[l][d] via all-ones A fragment
        bf16x8 ones;
#pragma unroll
        for (int j = 0; j < 8; ++j) ones[j] = (short)0x3F80;
        floatx4 zacc[4] = {};
#pragma unroll
        for (int n = 0; n < 4; ++n) {
            const bf16x8 kf0 = *(const bf16x8*)&Kt[(n * 16 + frow) * SP + fko];
            const bf16x8 kf1 = *(const bf16x8*)&Kt[(n * 16 + frow) * SP + 32 + fko];
            zacc[n] = __builtin_amdgcn_mfma_f32_16x16x32_bf16(ones, kf0, zacc[n], 0, 0, 0);
            zacc[n] = __builtin_amdgcn_mfma_f32_16x16x32_bf16(ones, kf1, zacc[n], 0, 0, 0);
        }
        if (quad == 0) {
#pragma unroll
            for (int n = 0; n < 4; ++n)
                zc[(size_t)(h * NCHUNK + c) * 64 + n * 16 + frow] = zacc[n][0];
        }
    }

    // ---- last-finisher election (release: fence all lanes, then atomic) ----
    __threadfence();
    __syncthreads();
    if (tid == 0) {
        const int prev = atomicAdd(&cnt[h], 1);
        isLast = (prev == NCHUNK - 1);
    }
    __syncthreads();
    if (!isLast) return;
    __threadfence();   // acquire side

    // ---- exclusive scan for head h: 16 (e,d) per thread, 4-deep batches ----
    {
        const int ed0 = tid * 16;
        const int e  = ed0 >> 6;
        const int d0 = ed0 & 63;
        const short* src = ScTb + (size_t)h * NCHUNK * 4096 + ed0;
        float s[16];
#pragma unroll
        for (int j = 0; j < 16; ++j) s[j] = 0.f;
        for (int cb = 0; cb < NCHUNK; cb += 4) {
            bf16x8 v0[4], v1[4];
#pragma unroll
            for (int u = 0; u < 4; ++u) {
                v0[u] = *(const bf16x8*)(src + (size_t)(cb + u) * 4096);
                v1[u] = *(const bf16x8*)(src + (size_t)(cb + u) * 4096 + 8);
            }
#pragma unroll
            for (int u = 0; u < 4; ++u) {
                bf16x8 o0, o1;
#pragma unroll
                for (int j = 0; j < 8; ++j) { o0[j] = f2bf(s[j]); o1[j] = f2bf(s[8 + j]); }
                short* dst = S0b + ((size_t)((h * NCHUNK + cb + u) * 65 + e)) * 64 + d0;
                *(bf16x8*)dst       = o0;
                *(bf16x8*)(dst + 8) = o1;
#pragma unroll
                for (int j = 0; j < 8; ++j) {
                    s[j]     += bf2f(v0[u][j]);
                    s[8 + j] += bf2f(v1[u][j]);
                }
            }
        }
    }
    if (tid < 64) {    // z0 row (row 64)
        float rz = 0.f;
        const float* zp = zc + (size_t)h * NCHUNK * 64 + tid;
        for (int cb = 0; cb < NCHUNK; cb += 8) {
            float w[8];
#pragma unroll
            for (int u = 0; u < 8; ++u) w[u] = zp[(size_t)(cb + u) * 64];
#pragma unroll
            for (int u = 0; u < 8; ++u) {
                S0b[((size_t)((h * NCHUNK + cb + u) * 65 + 64)) * 64 + tid] = f2bf(rz);
                rz += w[u];
            }
        }
    }
}

// ---------------------------------------------------------------------------
// K4: per-(head,chunk) intra-chunk attention, slim version (round-6 proven).
// Q/K/S0 fragments direct from global; only V^T and As in LDS (18.6 KB).
// ---------------------------------------------------------------------------
__global__ __launch_bounds__(256)
void chunk_attn(const short* __restrict__ Qb, const short* __restrict__ Kb,
                const short* __restrict__ Vb, const short* __restrict__ S0b,
                short* __restrict__ attn)
{
    __shared__ __align__(16) short Vs[65 * SP];   // V^T, row 64 = ones
    __shared__ __align__(16) short As[64 * SP];
    const int c = blockIdx.x, h = blockIdx.y;
    const int tid = threadIdx.x, lane = tid & 63, wave = tid >> 6;
    const size_t rb = ((size_t)h * L_SEQ + (size_t)c * CHUNK) * HD;
    const short* Qg = Qb + rb;
    const short* Kg = Kb + rb;
    const short* Vg = Vb + rb;
    const short* Sg = S0b + (size_t)(h * NCHUNK + c) * 65 * 64;

#pragma unroll
    for (int q = 0; q < 2; ++q) {
        const int idx = q * 256 + tid;
        const int row = idx >> 3, c8 = (idx & 7) << 3;
        const bf16x8 vv = *(const bf16x8*)&Vg[row * 64 + c8];
#pragma unroll
        for (int j = 0; j < 8; ++j) Vs[(c8 + j) * SP + row] = vv[j];   // V^T
    }
    if (tid < 64) Vs[64 * SP + tid] = (short)0x3F80;                   // ones
    __syncthreads();

    const int frow = lane & 15;
    const int quad = lane >> 4;
    const int fko  = quad << 3;
    const int wm   = wave << 4;

    const bf16x8 qf0 = *(const bf16x8*)&Qg[(wm + frow) * 64 + fko];
    const bf16x8 qf1 = *(const bf16x8*)&Qg[(wm + frow) * 64 + 32 + fko];

    floatx4 sacc[4] = {};
#pragma unroll
    for (int n = 0; n < 4; ++n) {
        const bf16x8 kf0 = *(const bf16x8*)&Kg[(n * 16 + frow) * 64 + fko];
        const bf16x8 kf1 = *(const bf16x8*)&Kg[(n * 16 + frow) * 64 + 32 + fko];
        sacc[n] = __builtin_amdgcn_mfma_f32_16x16x32_bf16(qf0, kf0, sacc[n], 0, 0, 0);
        sacc[n] = __builtin_amdgcn_mfma_f32_16x16x32_bf16(qf1, kf1, sacc[n], 0, 0, 0);
    }
#pragma unroll
    for (int n = 0; n < 4; ++n)
#pragma unroll
        for (int r = 0; r < 4; ++r) {
            const int i = wm + quad * 4 + r;
            const int j = n * 16 + frow;
            As[i * SP + j] = (j <= i) ? f2bf(sacc[n][r]) : (short)0;
        }
    const bf16x8 af0 = *(const bf16x8*)&As[(wm + frow) * SP + fko];
    const bf16x8 af1 = *(const bf16x8*)&As[(wm + frow) * SP + 32 + fko];

    floatx4 oacc[5] = {};
#pragma unroll
    for (int n = 0; n < 4; ++n) {
        const bf16x8 vf0 = *(const bf16x8*)&Vs[(n * 16 + frow) * SP + fko];
        const bf16x8 vf1 = *(const bf16x8*)&Vs[(n * 16 + frow) * SP + 32 + fko];
        oacc[n] = __builtin_amdgcn_mfma_f32_16x16x32_bf16(af0, vf0, oacc[n], 0, 0, 0);
        oacc[n] = __builtin_amdgcn_mfma_f32_16x16x32_bf16(af1, vf1, oacc[n], 0, 0, 0);
        const bf16x8 sf0 = *(const bf16x8*)&Sg[(n * 16 + frow) * 64 + fko];
        const bf16x8 sf1 = *(const bf16x8*)&Sg[(n * 16 + frow) * 64 + 32 + fko];
        oacc[n] = __builtin_amdgcn_mfma_f32_16x16x32_bf16(qf0, sf0, oacc[n], 0, 0, 0);
        oacc[n] = __builtin_amdgcn_mfma_f32_16x16x32_bf16(qf1, sf1, oacc[n], 0, 0, 0);
    }
    {   // tile 4: broadcast row 64 (ones / z0) -> col 64 = norm
        const bf16x8 vf0 = *(const bf16x8*)&Vs[64 * SP + fko];
        const bf16x8 vf1 = *(const bf16x8*)&Vs[64 * SP + 32 + fko];
        oacc[4] = __builtin_amdgcn_mfma_f32_16x16x32_bf16(af0, vf0, oacc[4], 0, 0, 0);
        oacc[4] = __builtin_amdgcn_mfma_f32_16x16x32_bf16(af1, vf1, oacc[4], 0, 0, 0);
        const bf16x8 sf0 = *(const bf16x8*)&Sg[64 * 64 + fko];
        const bf16x8 sf1 = *(const bf16x8*)&Sg[64 * 64 + 32 + fko];
        oacc[4] = __builtin_amdgcn_mfma_f32_16x16x32_bf16(qf0, sf0, oacc[4], 0, 0, 0);
        oacc[4] = __builtin_amdgcn_mfma_f32_16x16x32_bf16(qf1, sf1, oacc[4], 0, 0, 0);
    }
#pragma unroll
    for (int r = 0; r < 4; ++r) {
        const float norm = __shfl(oacc[4][r], lane & 48) + EPS;
        const float inv = 1.f / norm;
        const int i = wm + quad * 4 + r;
#pragma unroll
        for (int n = 0; n < 4; ++n)
            As[i * SP + n * 16 + frow] = f2bf(oacc[n][r] * inv);
    }
    __syncthreads();
#pragma unroll
    for (int t = 0; t < 2; ++t) {
        const int idx = t * 256 + tid;
        const int row = idx >> 3, c8 = (idx & 7) << 3;
        *(bf16x8*)&attn[(size_t)(c * CHUNK + row) * EMB + h * HD + c8] =
            *(const bf16x8*)&As[row * SP + c8];
    }
}

// ---------------------------------------------------------------------------
extern "C" void kernel_launch(void* const* d_in, const int* in_sizes, int n_in,
                              void* d_out, int out_size, void* d_ws, size_t ws_size,
                              hipStream_t stream)
{
    const float* x     = (const float*)d_in[0];
    const float* qkv_w = (const float*)d_in[1];
    const float* qkv_b = (const float*)d_in[2];
    const float* out_w = (const float*)d_in[3];
    const float* out_b = (const float*)d_in[4];
    float* out = (float*)d_out;

    short* ws    = (short*)d_ws;
    short* Qb    = ws;                   // head-major bf16, 4194304 each
    short* Kb    = Qb + 4194304;
    short* Vb    = Kb + 4194304;
    short* xb    = Vb + 4194304;
    short* qwt   = xb + 4194304;         // 3072 x 1024
    short* owt   = qwt + 3145728;        // 1024 x 1024
    short* attnb = owt + 1048576;        // 4096 x 1024
    short* ScTb  = attnb + 4194304;      // 1024 * 64 * 64
    short* S0b   = ScTb + 4194304;       // 1024 * 65 * 64
    float* zc    = (float*)(S0b + 4259840);    // 65536 fp32
    int*   cnt   = (int*)(zc + 65536);         // 16 per-head scan counters

    prep<<<dim3(3072), 256, 0, stream>>>(x, xb, qkv_w, qwt, out_w, owt, cnt);
    mfma_gemm_qkv<<<dim3(N3 / 128, L_SEQ / 128), 256, 0, stream>>>(
        xb, qwt, qkv_b, Qb, Kb, Vb, N3, EMB);
    chunk_state<<<dim3(NCHUNK, NH), 256, 0, stream>>>(Kb, Vb, ScTb, zc, S0b, cnt);
    chunk_attn<<<dim3(NCHUNK, NH), 256, 0, stream>>>(Qb, Kb, Vb, S0b, attnb);
    mfma_gemm_out<<<dim3(EMB / 128, L_SEQ / 64), 256, 0, stream>>>(
        attnb, owt, out_b, out, EMB, EMB);
}

// Round 12
// 163.597 us; speedup vs baseline: 2.0813x; 2.0813x over previous
//
#include <hip/hip_runtime.h>
#include <cstddef>
#include <cstdint>

#define L_SEQ 4096
#define EMB   1024
#define NH    16
#define HD    64
#define N3    3072
#define CHUNK 64
#define NCHUNK 64
#define EPS 1e-6f

typedef __attribute__((ext_vector_type(8))) short   bf16x8;
typedef __attribute__((ext_vector_type(4))) short   bf16x4;
typedef __attribute__((ext_vector_type(4))) float   floatx4;

#define AS1 __attribute__((address_space(1)))
#define AS3 __attribute__((address_space(3)))

__device__ __forceinline__ void gload_lds16(const void* g, void* l) {
    __builtin_amdgcn_global_load_lds((AS1 const unsigned int*)g,
                                     (AS3 unsigned int*)l, 16, 0, 0);
}

// round-to-nearest-even fp32 -> bf16 bits
__device__ __forceinline__ short f2bf(float f) {
    union { float f; unsigned u; } a; a.f = f;
    unsigned r = a.u + 0x7fffu + ((a.u >> 16) & 1u);
    return (short)(r >> 16);
}
__device__ __forceinline__ float bf2f(short s) {
    union { unsigned u; float f; } a; a.u = ((unsigned)(unsigned short)s) << 16;
    return a.f;
}

// ---------------------------------------------------------------------------
// K0: fused prep — blocks [0,2048): x->bf16; [2048,2816): qkv_w^T;
// [2816,3072): out_w^T.
// ---------------------------------------------------------------------------
__device__ __forceinline__ void transpose_tile(const float* __restrict__ W,
                                               short* __restrict__ WT,
                                               int K, int N, int bx, int by,
                                               float (*t)[65], int tid)
{
    const int r  = tid >> 4;
    const int c4 = (tid & 15) << 2;
#pragma unroll
    for (int s = 0; s < 4; ++s) {
        const int k = r + s * 16;
        const floatx4 v = *(const floatx4*)&W[(size_t)(by * 64 + k) * N + bx * 64 + c4];
        t[k][c4 + 0] = v[0]; t[k][c4 + 1] = v[1];
        t[k][c4 + 2] = v[2]; t[k][c4 + 3] = v[3];
    }
    __syncthreads();
#pragma unroll
    for (int s = 0; s < 4; ++s) {
        const int n = r + s * 16;
        bf16x4 o;
        o[0] = f2bf(t[c4 + 0][n]); o[1] = f2bf(t[c4 + 1][n]);
        o[2] = f2bf(t[c4 + 2][n]); o[3] = f2bf(t[c4 + 3][n]);
        *(bf16x4*)&WT[(size_t)(bx * 64 + n) * K + by * 64 + c4] = o;
    }
}

__global__ __launch_bounds__(256)
void prep(const float* __restrict__ x, short* __restrict__ xb,
          const float* __restrict__ qkv_w, short* __restrict__ qwt,
          const float* __restrict__ out_w, short* __restrict__ owt)
{
    __shared__ float t[64][65];
    const int b = blockIdx.x;
    const int tid = threadIdx.x;
    if (b < 2048) {
        const int i = b * 256 + tid;
        const floatx4 a = *(const floatx4*)(x + (size_t)i * 8);
        const floatx4 c = *(const floatx4*)(x + (size_t)i * 8 + 4);
        bf16x8 o;
        o[0] = f2bf(a[0]); o[1] = f2bf(a[1]); o[2] = f2bf(a[2]); o[3] = f2bf(a[3]);
        o[4] = f2bf(c[0]); o[5] = f2bf(c[1]); o[6] = f2bf(c[2]); o[7] = f2bf(c[3]);
        *(bf16x8*)(xb + (size_t)i * 8) = o;
    } else if (b < 2048 + 768) {
        const int u = b - 2048;
        transpose_tile(qkv_w, qwt, EMB, N3, u % 48, u / 48, t, tid);
    } else {
        const int u = b - 2816;
        transpose_tile(out_w, owt, EMB, EMB, u & 15, u >> 4, t, tid);
    }
}

// ---------------------------------------------------------------------------
// K1: qkv GEMM, 128x128 tile, double-panel K-step (16 barrier pairs).
// Epilogue: bias + elu+1 on q/k, LDS repack, coalesced bf16x8 scatter.
// ---------------------------------------------------------------------------
#define CST 136

__global__ __launch_bounds__(256)
void mfma_gemm_qkv(const short* __restrict__ A, const short* __restrict__ BT,
                   const float* __restrict__ bias,
                   short* __restrict__ OQ, short* __restrict__ OK,
                   short* __restrict__ OV, int N, int K)
{
    __shared__ __align__(16) short smem[128 * CST];
    short* pan[4] = { smem, smem + 4096, smem + 8192, smem + 12288 };
    const int tid  = threadIdx.x;
    const int lane = tid & 63;
    const int wave = tid >> 6;
    const int wm = (wave >> 1) * 64;
    const int wn = (wave & 1) * 64;
    const int bx = blockIdx.x;
    const int by = blockIdx.y;
    const int frow = lane & 15;
    const int quad = lane >> 4;
    const int fko  = quad << 3;

    const short* Ab = A  + (size_t)(by * 128) * K;
    const short* Bb = BT + (size_t)(bx * 128) * K;

    floatx4 acc[4][4] = {};

    for (int k0 = 0; k0 < K; k0 += 64) {
#pragma unroll
        for (int p = 0; p < 2; ++p) {
            const int kp = k0 + p * 32;
#pragma unroll
            for (int q = 0; q < 2; ++q) {
                const int ia = q * 256 + tid;
                const int row = ia >> 2;
                const int kc  = (ia & 3) << 3;
                gload_lds16(Ab + (size_t)row * K + kp + kc, &pan[p * 2 + 0][ia << 3]);
                gload_lds16(Bb + (size_t)row * K + kp + kc, &pan[p * 2 + 1][ia << 3]);
            }
        }
        __syncthreads();
#pragma unroll
        for (int p = 0; p < 2; ++p) {
            bf16x8 af[4], bfv[4];
#pragma unroll
            for (int mi = 0; mi < 4; ++mi)
                af[mi] = *(const bf16x8*)&pan[p * 2 + 0][(wm + mi * 16 + frow) * 32 + fko];
#pragma unroll
            for (int ni = 0; ni < 4; ++ni)
                bfv[ni] = *(const bf16x8*)&pan[p * 2 + 1][(wn + ni * 16 + frow) * 32 + fko];
#pragma unroll
            for (int mi = 0; mi < 4; ++mi)
#pragma unroll
                for (int ni = 0; ni < 4; ++ni)
                    acc[mi][ni] = __builtin_amdgcn_mfma_f32_16x16x32_bf16(
                        af[mi], bfv[ni], acc[mi][ni], 0, 0, 0);
        }
        __syncthreads();
    }

    const int rq = quad << 2;
#pragma unroll
    for (int ni = 0; ni < 4; ++ni) {
        const int n = bx * 128 + wn + ni * 16 + frow;
        const float bv = bias[n];
        const bool do_elu = (n >> 10) < 2;
#pragma unroll
        for (int mi = 0; mi < 4; ++mi)
#pragma unroll
            for (int r = 0; r < 4; ++r) {
                float v = acc[mi][ni][r] + bv;
                if (do_elu) v = (v > 0.f) ? (v + 1.f) : __expf(v);
                smem[(wm + mi * 16 + rq + r) * CST + wn + ni * 16 + frow] = f2bf(v);
            }
    }
    __syncthreads();
#pragma unroll
    for (int t = 0; t < 8; ++t) {
        const int idx = t * 256 + tid;
        const int mm = idx >> 4;
        const int c8 = (idx & 15) << 3;
        const bf16x8 val = *(const bf16x8*)&smem[mm * CST + c8];
        const int n0 = bx * 128 + c8;
        const int rsel = n0 >> 10;
        const int h  = (n0 & 1023) >> 6;
        const int d  = n0 & 63;
        short* base = (rsel == 0) ? OQ : (rsel == 1 ? OK : OV);
        *(bf16x8*)&base[((size_t)(h * L_SEQ + by * 128 + mm)) * HD + d] = val;
    }
}

// ---------------------------------------------------------------------------
// K5: out-projection GEMM, 64x128 tile (512 blocks = 2/CU), double-panel.
// ---------------------------------------------------------------------------
__global__ __launch_bounds__(256)
void mfma_gemm_out(const short* __restrict__ A, const short* __restrict__ BT,
                   const float* __restrict__ bias, float* __restrict__ OF,
                   int N, int K)
{
    __shared__ __align__(16) short smem[12288];
    short* pan[4] = { smem, smem + 2048, smem + 6144, smem + 8192 };
    const int tid  = threadIdx.x;
    const int lane = tid & 63;
    const int wave = tid >> 6;
    const int wm = (wave >> 1) * 32;
    const int wn = (wave & 1) * 64;
    const int bx = blockIdx.x;
    const int by = blockIdx.y;
    const int frow = lane & 15;
    const int quad = lane >> 4;
    const int fko  = quad << 3;

    const short* Ab = A  + (size_t)(by * 64) * K;
    const short* Bb = BT + (size_t)(bx * 128) * K;

    floatx4 acc[2][4] = {};

    for (int k0 = 0; k0 < K; k0 += 64) {
#pragma unroll
        for (int p = 0; p < 2; ++p) {
            const int kp = k0 + p * 32;
            {
                const int row = tid >> 2;
                const int kc  = (tid & 3) << 3;
                gload_lds16(Ab + (size_t)row * K + kp + kc, &pan[p * 2 + 0][tid << 3]);
            }
#pragma unroll
            for (int q = 0; q < 2; ++q) {
                const int ib = q * 256 + tid;
                const int row = ib >> 2;
                const int kc  = (ib & 3) << 3;
                gload_lds16(Bb + (size_t)row * K + kp + kc, &pan[p * 2 + 1][ib << 3]);
            }
        }
        __syncthreads();
#pragma unroll
        for (int p = 0; p < 2; ++p) {
            bf16x8 af[2], bfv[4];
#pragma unroll
            for (int mi = 0; mi < 2; ++mi)
                af[mi] = *(const bf16x8*)&pan[p * 2 + 0][(wm + mi * 16 + frow) * 32 + fko];
#pragma unroll
            for (int ni = 0; ni < 4; ++ni)
                bfv[ni] = *(const bf16x8*)&pan[p * 2 + 1][(wn + ni * 16 + frow) * 32 + fko];
#pragma unroll
            for (int mi = 0; mi < 2; ++mi)
#pragma unroll
                for (int ni = 0; ni < 4; ++ni)
                    acc[mi][ni] = __builtin_amdgcn_mfma_f32_16x16x32_bf16(
                        af[mi], bfv[ni], acc[mi][ni], 0, 0, 0);
        }
        __syncthreads();
    }

    const int rq = quad << 2;
#pragma unroll
    for (int ni = 0; ni < 4; ++ni) {
        const int n = bx * 128 + wn + ni * 16 + frow;
        const float bv = bias[n];
#pragma unroll
        for (int mi = 0; mi < 2; ++mi)
#pragma unroll
            for (int r = 0; r < 4; ++r) {
                const int m = by * 64 + wm + mi * 16 + rq + r;
                OF[(size_t)m * N + n] = acc[mi][ni][r] + bv;
            }
    }
}

// ---------------------------------------------------------------------------
// K2: per-(head,chunk) state sums, MFMA version.
//   ScTb[(h,c)][e][d] = sum_l V[l][e] K'[l][d]   (A = V^T, B = K'^T)
//   zc[(h,c)][d]      = sum_l K'[l][d]           (ones-A trick, wave 0)
// ---------------------------------------------------------------------------
#define SP 72

__global__ __launch_bounds__(256, 4)
void chunk_state(const short* __restrict__ Kb, const short* __restrict__ Vb,
                 short* __restrict__ ScTb, float* __restrict__ zc)
{
    __shared__ __align__(16) short Vt[64 * SP];   // V^T: rows e, cols l
    __shared__ __align__(16) short Kt[64 * SP];   // K'^T: rows d, cols l
    const int c = blockIdx.x, h = blockIdx.y;
    const int tid = threadIdx.x, lane = tid & 63, wave = tid >> 6;
    const int frow = lane & 15;
    const int quad = lane >> 4;
    const int fko  = quad << 3;
    const int wm   = wave << 4;
    const short* Kg = Kb + ((size_t)h * L_SEQ + (size_t)c * CHUNK) * HD;
    const short* Vg = Vb + ((size_t)h * L_SEQ + (size_t)c * CHUNK) * HD;

#pragma unroll
    for (int q = 0; q < 2; ++q) {
        const int idx = q * 256 + tid;            // 512 chunks of 8
        const int l = idx >> 3, c8 = (idx & 7) << 3;
        const bf16x8 vv = *(const bf16x8*)&Vg[l * 64 + c8];
        const bf16x8 kk = *(const bf16x8*)&Kg[l * 64 + c8];
#pragma unroll
        for (int j = 0; j < 8; ++j) {
            Vt[(c8 + j) * SP + l] = vv[j];
            Kt[(c8 + j) * SP + l] = kk[j];
        }
    }
    __syncthreads();

    const bf16x8 af0 = *(const bf16x8*)&Vt[(wm + frow) * SP + fko];
    const bf16x8 af1 = *(const bf16x8*)&Vt[(wm + frow) * SP + 32 + fko];

    floatx4 acc[4] = {};
#pragma unroll
    for (int n = 0; n < 4; ++n) {
        const bf16x8 kf0 = *(const bf16x8*)&Kt[(n * 16 + frow) * SP + fko];
        const bf16x8 kf1 = *(const bf16x8*)&Kt[(n * 16 + frow) * SP + 32 + fko];
        acc[n] = __builtin_amdgcn_mfma_f32_16x16x32_bf16(af0, kf0, acc[n], 0, 0, 0);
        acc[n] = __builtin_amdgcn_mfma_f32_16x16x32_bf16(af1, kf1, acc[n], 0, 0, 0);
    }

    short* Sout = ScTb + (size_t)(h * NCHUNK + c) * 4096;
#pragma unroll
    for (int n = 0; n < 4; ++n)
#pragma unroll
        for (int r = 0; r < 4; ++r) {
            const int e = wm + quad * 4 + r;
            const int d = n * 16 + frow;
            Sout[e * 64 + d] = f2bf(acc[n][r]);
        }

    if (wave == 0) {   // z[d] = sum_l K'[l][d] via all-ones A fragment
        bf16x8 ones;
#pragma unroll
        for (int j = 0; j < 8; ++j) ones[j] = (short)0x3F80;
        floatx4 zacc[4] = {};
#pragma unroll
        for (int n = 0; n < 4; ++n) {
            const bf16x8 kf0 = *(const bf16x8*)&Kt[(n * 16 + frow) * SP + fko];
            const bf16x8 kf1 = *(const bf16x8*)&Kt[(n * 16 + frow) * SP + 32 + fko];
            zacc[n] = __builtin_amdgcn_mfma_f32_16x16x32_bf16(ones, kf0, zacc[n], 0, 0, 0);
            zacc[n] = __builtin_amdgcn_mfma_f32_16x16x32_bf16(ones, kf1, zacc[n], 0, 0, 0);
        }
        if (quad == 0) {
#pragma unroll
            for (int n = 0; n < 4; ++n)
                zc[(size_t)(h * NCHUNK + c) * 64 + n * 16 + frow] = zacc[n][0];
        }
    }
}

// ---------------------------------------------------------------------------
// K3: exclusive prefix over chunks, 8-deep batched loads.
// S0b per (h,c): 65 rows x 64; rows 0..63 = S0^T[e][d], row 64 = z0[d].
// ---------------------------------------------------------------------------
__global__ __launch_bounds__(256)
void prefix_scan(const short* __restrict__ ScTb, const float* __restrict__ zc,
                 short* __restrict__ S0b)
{
    const int g = blockIdx.x * 256 + threadIdx.x;
    const int h  = g >> 12;
    const int ed = g & 4095;
    const int e  = ed >> 6;
    const int d  = ed & 63;
    const short* src = ScTb + (size_t)h * NCHUNK * 4096 + ed;
    float run = 0.f;
    for (int cb = 0; cb < NCHUNK; cb += 8) {
        short v[8];
#pragma unroll
        for (int u = 0; u < 8; ++u) v[u] = src[(size_t)(cb + u) * 4096];
#pragma unroll
        for (int u = 0; u < 8; ++u) {
            S0b[((size_t)((h * NCHUNK + cb + u) * 65 + e)) * 64 + d] = f2bf(run);
            run += bf2f(v[u]);
        }
    }
    if (g < NH * HD) {
        const int h2 = g >> 6, d2 = g & 63;
        float rz = 0.f;
        for (int cb = 0; cb < NCHUNK; cb += 8) {
            float w[8];
#pragma unroll
            for (int u = 0; u < 8; ++u)
                w[u] = zc[((size_t)(h2 * NCHUNK + cb + u)) * HD + d2];
#pragma unroll
            for (int u = 0; u < 8; ++u) {
                S0b[((size_t)((h2 * NCHUNK + cb + u) * 65 + 64)) * 64 + d2] = f2bf(rz);
                rz += w[u];
            }
        }
    }
}

// ---------------------------------------------------------------------------
// K4: per-(head,chunk) intra-chunk attention, slim version.
// Q/K/S0 fragments direct from global; only V^T and As in LDS (18.6 KB).
// ---------------------------------------------------------------------------
__global__ __launch_bounds__(256)
void chunk_attn(const short* __restrict__ Qb, const short* __restrict__ Kb,
                const short* __restrict__ Vb, const short* __restrict__ S0b,
                short* __restrict__ attn)
{
    __shared__ __align__(16) short Vs[65 * SP];   // V^T, row 64 = ones
    __shared__ __align__(16) short As[64 * SP];
    const int c = blockIdx.x, h = blockIdx.y;
    const int tid = threadIdx.x, lane = tid & 63, wave = tid >> 6;
    const size_t rb = ((size_t)h * L_SEQ + (size_t)c * CHUNK) * HD;
    const short* Qg = Qb + rb;
    const short* Kg = Kb + rb;
    const short* Vg = Vb + rb;
    const short* Sg = S0b + (size_t)(h * NCHUNK + c) * 65 * 64;

#pragma unroll
    for (int q = 0; q < 2; ++q) {
        const int idx = q * 256 + tid;
        const int row = idx >> 3, c8 = (idx & 7) << 3;
        const bf16x8 vv = *(const bf16x8*)&Vg[row * 64 + c8];
#pragma unroll
        for (int j = 0; j < 8; ++j) Vs[(c8 + j) * SP + row] = vv[j];   // V^T
    }
    if (tid < 64) Vs[64 * SP + tid] = (short)0x3F80;                   // ones
    __syncthreads();

    const int frow = lane & 15;
    const int quad = lane >> 4;
    const int fko  = quad << 3;
    const int wm   = wave << 4;

    const bf16x8 qf0 = *(const bf16x8*)&Qg[(wm + frow) * 64 + fko];
    const bf16x8 qf1 = *(const bf16x8*)&Qg[(wm + frow) * 64 + 32 + fko];

    floatx4 sacc[4] = {};
#pragma unroll
    for (int n = 0; n < 4; ++n) {
        const bf16x8 kf0 = *(const bf16x8*)&Kg[(n * 16 + frow) * 64 + fko];
        const bf16x8 kf1 = *(const bf16x8*)&Kg[(n * 16 + frow) * 64 + 32 + fko];
        sacc[n] = __builtin_amdgcn_mfma_f32_16x16x32_bf16(qf0, kf0, sacc[n], 0, 0, 0);
        sacc[n] = __builtin_amdgcn_mfma_f32_16x16x32_bf16(qf1, kf1, sacc[n], 0, 0, 0);
    }
#pragma unroll
    for (int n = 0; n < 4; ++n)
#pragma unroll
        for (int r = 0; r < 4; ++r) {
            const int i = wm + quad * 4 + r;
            const int j = n * 16 + frow;
            As[i * SP + j] = (j <= i) ? f2bf(sacc[n][r]) : (short)0;
        }
    const bf16x8 af0 = *(const bf16x8*)&As[(wm + frow) * SP + fko];
    const bf16x8 af1 = *(const bf16x8*)&As[(wm + frow) * SP + 32 + fko];

    floatx4 oacc[5] = {};
#pragma unroll
    for (int n = 0; n < 4; ++n) {
        const bf16x8 vf0 = *(const bf16x8*)&Vs[(n * 16 + frow) * SP + fko];
        const bf16x8 vf1 = *(const bf16x8*)&Vs[(n * 16 + frow) * SP + 32 + fko];
        oacc[n] = __builtin_amdgcn_mfma_f32_16x16x32_bf16(af0, vf0, oacc[n], 0, 0, 0);
        oacc[n] = __builtin_amdgcn_mfma_f32_16x16x32_bf16(af1, vf1, oacc[n], 0, 0, 0);
        const bf16x8 sf0 = *(const bf16x8*)&Sg[(n * 16 + frow) * 64 + fko];
        const bf16x8 sf1 = *(const bf16x8*)&Sg[(n * 16 + frow) * 64 + 32 + fko];
        oacc[n] = __builtin_amdgcn_mfma_f32_16x16x32_bf16(qf0, sf0, oacc[n], 0, 0, 0);
        oacc[n] = __builtin_amdgcn_mfma_f32_16x16x32_bf16(qf1, sf1, oacc[n], 0, 0, 0);
    }
    {   // tile 4: broadcast row 64 (ones / z0) -> col 64 = norm
        const bf16x8 vf0 = *(const bf16x8*)&Vs[64 * SP + fko];
        const bf16x8 vf1 = *(const bf16x8*)&Vs[64 * SP + 32 + fko];
        oacc[4] = __builtin_amdgcn_mfma_f32_16x16x32_bf16(af0, vf0, oacc[4], 0, 0, 0);
        oacc[4] = __builtin_amdgcn_mfma_f32_16x16x32_bf16(af1, vf1, oacc[4], 0, 0, 0);
        const bf16x8 sf0 = *(const bf16x8*)&Sg[64 * 64 + fko];
        const bf16x8 sf1 = *(const bf16x8*)&Sg[64 * 64 + 32 + fko];
        oacc[4] = __builtin_amdgcn_mfma_f32_16x16x32_bf16(qf0, sf0, oacc[4], 0, 0, 0);
        oacc[4] = __builtin_amdgcn_mfma_f32_16x16x32_bf16(qf1, sf1, oacc[4], 0, 0, 0);
    }
#pragma unroll
    for (int r = 0; r < 4; ++r) {
        const float norm = __shfl(oacc[4][r], lane & 48) + EPS;
        const float inv = 1.f / norm;
        const int i = wm + quad * 4 + r;
#pragma unroll
        for (int n = 0; n < 4; ++n)
            As[i * SP + n * 16 + frow] = f2bf(oacc[n][r] * inv);
    }
    __syncthreads();
#pragma unroll
    for (int t = 0; t < 2; ++t) {
        const int idx = t * 256 + tid;
        const int row = idx >> 3, c8 = (idx & 7) << 3;
        *(bf16x8*)&attn[(size_t)(c * CHUNK + row) * EMB + h * HD + c8] =
            *(const bf16x8*)&As[row * SP + c8];
    }
}

// ---------------------------------------------------------------------------
extern "C" void kernel_launch(void* const* d_in, const int* in_sizes, int n_in,
                              void* d_out, int out_size, void* d_ws, size_t ws_size,
                              hipStream_t stream)
{
    const float* x     = (const float*)d_in[0];
    const float* qkv_w = (const float*)d_in[1];
    const float* qkv_b = (const float*)d_in[2];
    const float* out_w = (const float*)d_in[3];
    const float* out_b = (const float*)d_in[4];
    float* out = (float*)d_out;

    short* ws    = (short*)d_ws;
    short* Qb    = ws;                   // head-major bf16, 4194304 each
    short* Kb    = Qb + 4194304;
    short* Vb    = Kb + 4194304;
    short* xb    = Vb + 4194304;
    short* qwt   = xb + 4194304;         // 3072 x 1024
    short* owt   = qwt + 3145728;        // 1024 x 1024
    short* attnb = owt + 1048576;        // 4096 x 1024
    short* ScTb  = attnb + 4194304;      // 1024 * 64 * 64
    short* S0b   = ScTb + 4194304;       // 1024 * 65 * 64
    float* zc    = (float*)(S0b + 4259840);    // 65536 fp32

    prep<<<dim3(3072), 256, 0, stream>>>(x, xb, qkv_w, qwt, out_w, owt);
    mfma_gemm_qkv<<<dim3(N3 / 128, L_SEQ / 128), 256, 0, stream>>>(
        xb, qwt, qkv_b, Qb, Kb, Vb, N3, EMB);
    chunk_state<<<dim3(NCHUNK, NH), 256, 0, stream>>>(Kb, Vb, ScTb, zc);
    prefix_scan<<<dim3((NH * 4096) / 256), 256, 0, stream>>>(ScTb, zc, S0b);
    chunk_attn<<<dim3(NCHUNK, NH), 256, 0, stream>>>(Qb, Kb, Vb, S0b, attnb);
    mfma_gemm_out<<<dim3(EMB / 128, L_SEQ / 64), 256, 0, stream>>>(
        attnb, owt, out_b, out, EMB, EMB);
}